// Round 8
// baseline (11810.908 us; speedup 1.0000x reference)
//
#include <hip/hip_runtime.h>
#include <hip/hip_bf16.h>
#include <stdint.h>

#define B_SZ 8192
#define T_SZ 24
#define H_SZ 1024
#define G4   4096   // 4*H

typedef __attribute__((ext_vector_type(8))) short bf16x8;
typedef __attribute__((ext_vector_type(16))) float f32x16;

// Gate permutation for 32x32 MFMA epilogue: within each 64-col pair-group,
// cols 0-15 = gate i, 16-31 = f, 32-47 = g, 48-63 = o, for 16 units.
// (tile0 32 cols = [i|f], tile1 = [g|o]; lane&15 = unit, lane&16 = gate parity)
__device__ __forceinline__ int perm_old(int p) {
    int gate = ((p >> 5) & 1) * 2 + ((p >> 4) & 1);
    int unit = ((p >> 6) << 4) | (p & 15);
    return gate * 1024 + unit;
}
__device__ __forceinline__ int swz8(int r) { return (r ^ (r >> 3)) & 7; }

__device__ __forceinline__ float fast_sigmoid(float x) {
    return 1.f / (1.f + __expf(-x));
}
__device__ __forceinline__ float fast_tanh(float x) {
    float ax = __builtin_fabsf(x);
    float e  = __expf(2.f * ax);
    float r  = 1.f - 2.f / (e + 1.f);
    return __builtin_copysignf(r, x);
}

// ---------------- prep kernels ----------------
__global__ void k_prep_w1(const float* __restrict__ Whh1, __hip_bfloat16* __restrict__ dst) {
    int i = blockIdx.x * blockDim.x + threadIdx.x;   // over 4096*1024
    int p = i >> 10, k = i & 1023;
    dst[i] = __float2bfloat16(Whh1[(size_t)perm_old(p) * 1024 + k]);
}

__global__ void k_prep_w2(const float* __restrict__ Wih2, const float* __restrict__ Whh2,
                          __hip_bfloat16* __restrict__ dst) {
    int i = blockIdx.x * blockDim.x + threadIdx.x;   // over 4096*2048
    int p = i >> 11, k = i & 2047;
    int old = perm_old(p);
    float v = (k < 1024) ? Wih2[(size_t)old * 1024 + k] : Whh2[(size_t)old * 1024 + (k - 1024)];
    dst[i] = __float2bfloat16(v);
}

// biases stay in ORIGINAL gate-major layout (epilogue indexes bias[g*1024+u])
__global__ void k_prep_vec(const float* __restrict__ bih1, const float* __restrict__ bhh1,
                           const float* __restrict__ bih2, const float* __restrict__ bhh2,
                           float* __restrict__ b1p, float* __restrict__ b2p) {
    int p = blockIdx.x * blockDim.x + threadIdx.x;
    if (p >= G4) return;
    b1p[p] = bih1[p] + bhh1[p];
    b2p[p] = bih2[p] + bhh2[p];
}

__global__ void k_xT(const float* __restrict__ x, float* __restrict__ xT) {
    int i = blockIdx.x * blockDim.x + threadIdx.x;   // over B*T
    if (i >= B_SZ * T_SZ) return;
    int b = i / T_SZ, t = i % T_SZ;
    xT[t * B_SZ + b] = x[i];
}

__global__ void k_init_state(const float* __restrict__ h1_0, const float* __restrict__ c1_0,
                             const float* __restrict__ h2_0, const float* __restrict__ c2_0,
                             __hip_bfloat16* __restrict__ A2_0, __hip_bfloat16* __restrict__ A2_1,
                             float* __restrict__ c1, float* __restrict__ c2) {
    int i = blockIdx.x * blockDim.x + threadIdx.x;   // over B*H
    if (i >= B_SZ * H_SZ) return;
    int b = i >> 10, j = i & 1023;
    A2_1[(size_t)b * 2048 + j]        = __float2bfloat16(h1_0[i]);
    A2_0[(size_t)b * 2048 + 1024 + j] = __float2bfloat16(h2_0[i]);
    c1[i] = c1_0[i];
    c2[i] = c2_0[i];
}

// ---------------- fused GEMM + LSTM cell, 256x256, 32x32x16 MFMA ----------------
// 8 waves (2M x 4N), per-wave 128x64 C via 4m x 2n tiles of 32x32, BK=64.
// Grid 256: block = (m-block, n-PAIR); npair = bid&7 == XCD (round-robin) so each
// XCD's W-slab (2 n-blocks) stays L2-resident across both halves (weight-stationary).
// 4-phase K-loop identical to r7 skeleton (stage u1,u3@p2 / u4@p3 / u2@p4 into
// region-recycled buffers; ONE vmcnt(8) per K-tile at p4-end).
// Swizzle: chunk ^= swz8(row) (involution, pre-swizzled global source, linear LDS).
// 32x32x16 frags: A row=lane&31, k=(lane>>5)*8..+7; C col=lane&31,
// row=(reg&3)+8*(reg>>2)+4*(lane>>5)  [guide m74/m101].
#define BM 256
#define BN 256
#define BK 64

template<int LAYER>
__global__ __launch_bounds__(512, 2)
void k_gemm_cell(const __hip_bfloat16* __restrict__ A, int lda,
                 const __hip_bfloat16* __restrict__ Bw, int ldb, int K,
                 const float* __restrict__ biasp, const float* __restrict__ wih1,
                 const float* __restrict__ xT, int t,
                 float* __restrict__ c, __hip_bfloat16* __restrict__ hout) {
    __shared__ short As[2][BM][BK];   // 64 KiB
    __shared__ short Bs[2][BN][BK];   // 64 KiB
    const int lane = threadIdx.x & 63;
    const int wid  = threadIdx.x >> 6;    // 0..7

    const int bid   = blockIdx.x;
    const int npair = bid & 7;            // == XCD (perf heuristic only)
    const int m0    = (bid >> 3) * BM;    // 0..31 m-blocks

    const int wm  = wid >> 2;             // 0..1
    const int wn  = wid & 3;              // 0..3
    const int l31 = lane & 31;
    const int kg  = lane >> 5;            // 0..1 (k-group of 8)

    const __hip_bfloat16* Abase = A + (size_t)m0 * lda;
    const int NK = K >> 6;

    for (int half = 0; half < 2; ++half) {
        const int n0 = (npair * 2 + half) * BN;
        const __hip_bfloat16* Bbase = Bw + (size_t)n0 * ldb;

        f32x16 acc[4][2];
#pragma unroll
        for (int ii = 0; ii < 4; ++ii)
#pragma unroll
            for (int jj = 0; jj < 2; ++jj) acc[ii][jj] = (f32x16)0.f;

        // one global_load_lds covers 8 LDS rows; source col pre-swizzled so
        // linear LDS dest + same-XOR read = involution (rule #21).
        auto stage8A = [&](int buf, int lr0, int kcol) {
            int lr = lr0 + (lane >> 3);
            int scol = (((lane & 7) ^ swz8(lr)) << 3);
            const __hip_bfloat16* gp = Abase + (size_t)lr * lda + kcol + scol;
            __builtin_amdgcn_global_load_lds(
                (const __attribute__((address_space(1))) void*)gp,
                (__attribute__((address_space(3))) void*)(&As[buf][lr0][0]), 16, 0, 0);
        };
        auto stage8B = [&](int buf, int lr0, int kcol) {
            int lr = lr0 + (lane >> 3);
            int scol = (((lane & 7) ^ swz8(lr)) << 3);
            const __hip_bfloat16* gp = Bbase + (size_t)lr * ldb + kcol + scol;
            __builtin_amdgcn_global_load_lds(
                (const __attribute__((address_space(1))) void*)gp,
                (__attribute__((address_space(3))) void*)(&Bs[buf][lr0][0]), 16, 0, 0);
        };
        auto stage_u1 = [&](int kt, int buf) {   // A rows (r%128)<64  (mt 0,1)
#pragma unroll
            for (int j = 0; j < 2; ++j) {
                int rr0 = (wid * 2 + j) * 8;
                int lr0 = (rr0 < 64) ? rr0 : rr0 + 64;
                stage8A(buf, lr0, kt * BK);
            }
        };
        auto stage_u2 = [&](int kt, int buf) {   // A rows (r%128)>=64 (mt 2,3)
#pragma unroll
            for (int j = 0; j < 2; ++j) {
                int rr0 = (wid * 2 + j) * 8;
                int lr0 = (rr0 < 64) ? rr0 + 64 : rr0 + 128;
                stage8A(buf, lr0, kt * BK);
            }
        };
        auto stage_u3 = [&](int kt, int buf) {   // B rows (r%64)<32   (nt 0)
#pragma unroll
            for (int j = 0; j < 2; ++j) {
                int rr0 = (wid * 2 + j) * 8;
                int lr0 = ((rr0 >> 5) << 6) + (rr0 & 31);
                stage8B(buf, lr0, kt * BK);
            }
        };
        auto stage_u4 = [&](int kt, int buf) {   // B rows (r%64)>=32  (nt 1)
#pragma unroll
            for (int j = 0; j < 2; ++j) {
                int rr0 = (wid * 2 + j) * 8;
                int lr0 = ((rr0 >> 5) << 6) + 32 + (rr0 & 31);
                stage8B(buf, lr0, kt * BK);
            }
        };

        auto rdA = [&](const short* as, int mt, int ks) -> bf16x8 {
            int row = wm * 128 + mt * 32 + l31;
            int ch = (ks * 2 + kg) ^ swz8(row);
            return *(const bf16x8*)(as + row * 64 + ch * 8);
        };
        auto rdB = [&](const short* bs, int nt, int ks) -> bf16x8 {
            int row = wn * 64 + nt * 32 + l31;
            int ch = (ks * 2 + kg) ^ swz8(row);
            return *(const bf16x8*)(bs + row * 64 + ch * 8);
        };

        // ---- prologue: tile0 (u1,u3,u2,u4) then tile1 (u1,u3,u4,u2) ----
        stage_u1(0, 0); stage_u3(0, 0); stage_u2(0, 0); stage_u4(0, 0);
        stage_u1(1, 1); stage_u3(1, 1); stage_u4(1, 1); stage_u2(1, 1);
        asm volatile("s_waitcnt vmcnt(8)" ::: "memory");   // tile-0 landed
        __builtin_amdgcn_s_barrier();

        bf16x8 a0[2][4], a1[2][4], b0[4], b1[4];

        for (int kt = 0; kt < NK; ++kt) {
            const int buf = kt & 1;
            const short* as = buf ? &As[1][0][0] : &As[0][0][0];
            const short* bs = buf ? &Bs[1][0][0] : &Bs[0][0][0];

            // ---- phase 1: (mt01, nt0), 12 ds_reads, no stage ----
#pragma unroll
            for (int mt = 0; mt < 2; ++mt)
#pragma unroll
                for (int ks = 0; ks < 4; ++ks) a0[mt][ks] = rdA(as, mt, ks);
#pragma unroll
            for (int ks = 0; ks < 4; ++ks) b0[ks] = rdB(bs, 0, ks);
            asm volatile("s_waitcnt lgkmcnt(8)" ::: "memory");
            __builtin_amdgcn_s_barrier();
            asm volatile("s_waitcnt lgkmcnt(0)" ::: "memory");
            __builtin_amdgcn_s_setprio(1);
#pragma unroll
            for (int ks = 0; ks < 4; ++ks)
#pragma unroll
                for (int mt = 0; mt < 2; ++mt)
                    acc[mt][0] = __builtin_amdgcn_mfma_f32_32x32x16_bf16(a0[mt][ks], b0[ks], acc[mt][0], 0, 0, 0);
            __builtin_amdgcn_s_setprio(0);
            __builtin_amdgcn_s_barrier();

            // ---- phase 2: (mt01, nt1), 4 ds_reads, stage u1,u3[kt+2] ----
#pragma unroll
            for (int ks = 0; ks < 4; ++ks) b1[ks] = rdB(bs, 1, ks);
            if (kt + 2 < NK) { stage_u1(kt + 2, buf); stage_u3(kt + 2, buf); }
            __builtin_amdgcn_s_barrier();
            asm volatile("s_waitcnt lgkmcnt(0)" ::: "memory");
            __builtin_amdgcn_s_setprio(1);
#pragma unroll
            for (int ks = 0; ks < 4; ++ks)
#pragma unroll
                for (int mt = 0; mt < 2; ++mt)
                    acc[mt][1] = __builtin_amdgcn_mfma_f32_32x32x16_bf16(a0[mt][ks], b1[ks], acc[mt][1], 0, 0, 0);
            __builtin_amdgcn_s_setprio(0);
            __builtin_amdgcn_s_barrier();

            // ---- phase 3: (mt23, nt0), 8 ds_reads, stage u4[kt+2] ----
#pragma unroll
            for (int mt = 0; mt < 2; ++mt)
#pragma unroll
                for (int ks = 0; ks < 4; ++ks) a1[mt][ks] = rdA(as, 2 + mt, ks);
            if (kt + 2 < NK) stage_u4(kt + 2, buf);
            __builtin_amdgcn_s_barrier();
            asm volatile("s_waitcnt lgkmcnt(0)" ::: "memory");
            __builtin_amdgcn_s_setprio(1);
#pragma unroll
            for (int ks = 0; ks < 4; ++ks)
#pragma unroll
                for (int mt = 0; mt < 2; ++mt)
                    acc[2 + mt][0] = __builtin_amdgcn_mfma_f32_32x32x16_bf16(a1[mt][ks], b0[ks], acc[2 + mt][0], 0, 0, 0);
            __builtin_amdgcn_s_setprio(0);
            __builtin_amdgcn_s_barrier();

            // ---- phase 4: (mt23, nt1), 0 ds_reads, stage u2[kt+2] ----
            if (kt + 2 < NK) stage_u2(kt + 2, buf);
            __builtin_amdgcn_s_barrier();
            __builtin_amdgcn_s_setprio(1);
#pragma unroll
            for (int ks = 0; ks < 4; ++ks)
#pragma unroll
                for (int mt = 0; mt < 2; ++mt)
                    acc[2 + mt][1] = __builtin_amdgcn_mfma_f32_32x32x16_bf16(a1[mt][ks], b1[ks], acc[2 + mt][1], 0, 0, 0);
            __builtin_amdgcn_s_setprio(0);
            if (kt + 2 < NK)      asm volatile("s_waitcnt vmcnt(8)" ::: "memory");
            else if (kt + 1 < NK) asm volatile("s_waitcnt vmcnt(0)" ::: "memory");
            __builtin_amdgcn_s_barrier();
        }

        // ---- fused cell epilogue ----
        // lane owns unit u = U0 + (lane&15); gate parity by lane&16:
        // myhalf==0 lanes hold (i,g) planes, myhalf==1 hold (f,o); one
        // shfl_xor(16) exchange completes the quad; reg-halves split rows.
        const int U0 = ((n0 + wn * 64) >> 6) * 16;
        const int u  = U0 + (lane & 15);
        float bgi = biasp[u],        bgf = biasp[1024 + u];
        float bgg = biasp[2048 + u], bgo = biasp[3072 + u];
        float xwi = 0.f, xwf = 0.f, xwg = 0.f, xwo = 0.f;
        if (LAYER == 1) {
            xwi = wih1[u]; xwf = wih1[1024 + u]; xwg = wih1[2048 + u]; xwo = wih1[3072 + u];
        }
        const int myhalf = (lane >> 4) & 1;
        const int rext   = (lane >> 5) * 4;

#pragma unroll
        for (int mt = 0; mt < 4; ++mt) {
#pragma unroll
            for (int r = 0; r < 16; ++r) {
                float t0 = __shfl_xor(acc[mt][0][r], 16);
                float t1 = __shfl_xor(acc[mt][1][r], 16);
                if ((r >> 3) == myhalf) {
                    float gi = (myhalf ? t0 : acc[mt][0][r]) + bgi;
                    float gf = (myhalf ? acc[mt][0][r] : t0) + bgf;
                    float gg = (myhalf ? t1 : acc[mt][1][r]) + bgg;
                    float go = (myhalf ? acc[mt][1][r] : t1) + bgo;
                    int b = m0 + wm * 128 + mt * 32 + (r & 3) + 8 * (r >> 2) + rext;
                    if (LAYER == 1) {
                        float xv = xT[t * B_SZ + b];
                        gi += xv * xwi; gf += xv * xwf; gg += xv * xwg; go += xv * xwo;
                    }
                    float si = fast_sigmoid(gi);
                    float sf = fast_sigmoid(gf);
                    float so = fast_sigmoid(go);
                    float tg = fast_tanh(gg);
                    size_t ci = (size_t)b * H_SZ + u;
                    float cn = sf * c[ci] + si * tg;
                    c[ci] = cn;
                    hout[(size_t)b * 2048 + u] = __float2bfloat16(so * fast_tanh(cn));
                }
            }
        }
        __builtin_amdgcn_s_barrier();   // LDS safe before next half's staging
    }
}

// ---------------- output projection ----------------
__global__ __launch_bounds__(256)
void k_out(const __hip_bfloat16* __restrict__ h2base, const float* __restrict__ Wout,
           const float* __restrict__ bout, float* __restrict__ out) {
    int gw   = (blockIdx.x * blockDim.x + threadIdx.x) >> 6;
    int lane = threadIdx.x & 63;
    if (gw >= B_SZ) return;
    const __hip_bfloat16* h = h2base + (size_t)gw * 2048;
    float a0 = 0.f, a1 = 0.f;
#pragma unroll
    for (int k = lane; k < 1024; k += 64) {
        float hv = __bfloat162float(h[k]);
        a0 += hv * Wout[k];
        a1 += hv * Wout[1024 + k];
    }
    for (int off = 32; off; off >>= 1) {
        a0 += __shfl_down(a0, off);
        a1 += __shfl_down(a1, off);
    }
    if (lane == 0) {
        out[gw * 2 + 0] = a0 + bout[0];
        out[gw * 2 + 1] = a1 + bout[1];
    }
}

extern "C" void kernel_launch(void* const* d_in, const int* in_sizes, int n_in,
                              void* d_out, int out_size, void* d_ws, size_t ws_size,
                              hipStream_t stream) {
    const float* x    = (const float*)d_in[0];
    const float* h1_0 = (const float*)d_in[1];
    const float* c1_0 = (const float*)d_in[2];
    const float* h2_0 = (const float*)d_in[3];
    const float* c2_0 = (const float*)d_in[4];
    const float* Wih1 = (const float*)d_in[5];   // [4096,1] -> flat [4096], gate-major
    const float* Whh1 = (const float*)d_in[6];
    const float* bih1 = (const float*)d_in[7];
    const float* bhh1 = (const float*)d_in[8];
    const float* Wih2 = (const float*)d_in[9];
    const float* Whh2 = (const float*)d_in[10];
    const float* bih2 = (const float*)d_in[11];
    const float* bhh2 = (const float*)d_in[12];
    const float* Wout = (const float*)d_in[13];
    const float* bout = (const float*)d_in[14];
    float* out = (float*)d_out;
    (void)in_sizes; (void)n_in; (void)out_size; (void)ws_size;

    uint8_t* ws = (uint8_t*)d_ws;
    size_t off = 0;
    auto alloc = [&](size_t bytes) { void* p = ws + off; off += (bytes + 255) & ~(size_t)255; return p; };
    __hip_bfloat16* A2_0  = (__hip_bfloat16*)alloc((size_t)B_SZ * 2048 * 2);
    __hip_bfloat16* A2_1  = (__hip_bfloat16*)alloc((size_t)B_SZ * 2048 * 2);
    float*          c1    = (float*)alloc((size_t)B_SZ * H_SZ * 4);
    float*          c2    = (float*)alloc((size_t)B_SZ * H_SZ * 4);
    __hip_bfloat16* Whh1p = (__hip_bfloat16*)alloc((size_t)G4 * H_SZ * 2);
    __hip_bfloat16* Wcat2p= (__hip_bfloat16*)alloc((size_t)G4 * 2048 * 2);
    float*          bias1p= (float*)alloc(G4 * 4);
    float*          bias2p= (float*)alloc(G4 * 4);
    float*          xT    = (float*)alloc((size_t)T_SZ * B_SZ * 4);

    __hip_bfloat16* A2[2] = { A2_0, A2_1 };

    k_prep_w1<<<(G4 * H_SZ + 255) / 256, 256, 0, stream>>>(Whh1, Whh1p);
    k_prep_w2<<<(G4 * 2048 + 255) / 256, 256, 0, stream>>>(Wih2, Whh2, Wcat2p);
    k_prep_vec<<<(G4 + 255) / 256, 256, 0, stream>>>(bih1, bhh1, bih2, bhh2, bias1p, bias2p);
    k_xT<<<(B_SZ * T_SZ + 255) / 256, 256, 0, stream>>>(x, xT);
    k_init_state<<<(B_SZ * H_SZ + 255) / 256, 256, 0, stream>>>(h1_0, c1_0, h2_0, c2_0,
                                                                A2_0, A2_1, c1, c2);

    const int gemm_blocks = (B_SZ / BM) * (G4 / BN) / 2;   // 256: one block per CU, 2 n-tiles each

    for (int t = 0; t < T_SZ; ++t) {
        __hip_bfloat16* Pprev = A2[(t + 1) & 1];   // P_{t-1}
        __hip_bfloat16* Pt    = A2[t & 1];         // P_t
        // layer 1: reads h1_{t-1} (Pprev first half), writes h1_t -> Pt first half
        k_gemm_cell<1><<<gemm_blocks, 512, 0, stream>>>(
            (const __hip_bfloat16*)Pprev, 2048, Whh1p, 1024, 1024,
            bias1p, Wih1, xT, t, c1, Pt);
        // layer 2: reads [h1_t | h2_{t-1}] = Pt, writes h2_t -> P_{t+1} second half
        k_gemm_cell<2><<<gemm_blocks, 512, 0, stream>>>(
            (const __hip_bfloat16*)Pt, 2048, Wcat2p, 2048, 2048,
            bias2p, nullptr, nullptr, 0, c2, A2[(t + 1) & 1] + 1024);
    }
    // final h2 is in P_24 = A2[0] second half (T=24 even)
    k_out<<<(B_SZ * 64 + 255) / 256, 256, 0, stream>>>(A2_0 + 1024, Wout, bout, out);
}

// Round 9
// 5277.414 us; speedup vs baseline: 2.2380x; 2.2380x over previous
//
#include <hip/hip_runtime.h>
#include <hip/hip_bf16.h>
#include <stdint.h>

#define B_SZ 8192
#define T_SZ 24
#define H_SZ 1024
#define G4   4096   // 4*H

typedef __attribute__((ext_vector_type(8))) short bf16x8;
typedef __attribute__((ext_vector_type(4))) float f32x4;

// opaque LDS read: compiler cannot see the LDS dependence -> no auto vmcnt drains.
// base is a 32-bit LDS byte offset (AS3); imm is a compile-time byte offset.
#define DSR(dst, base, imm) \
    asm volatile("ds_read_b128 %0, %1 offset:" #imm : "=v"(dst) : "v"(base))

// Gate-interleaved permutation: new row p -> old row.
__device__ __forceinline__ int perm_old(int p) {
    int gate = (p >> 4) & 3;
    int unit = ((p >> 6) << 4) | (p & 15);
    return gate * 1024 + unit;
}

__device__ __forceinline__ float fast_sigmoid(float x) {
    return 1.f / (1.f + __expf(-x));
}
__device__ __forceinline__ float fast_tanh(float x) {
    float ax = __builtin_fabsf(x);
    float e  = __expf(2.f * ax);          // inf for large ax -> r = 1
    float r  = 1.f - 2.f / (e + 1.f);
    return __builtin_copysignf(r, x);
}

// ---------------- prep kernels (run once per launch) ----------------
__global__ void k_prep_w1(const float* __restrict__ Whh1, __hip_bfloat16* __restrict__ dst) {
    int i = blockIdx.x * blockDim.x + threadIdx.x;   // over 4096*1024
    int p = i >> 10, k = i & 1023;
    dst[i] = __float2bfloat16(Whh1[(size_t)perm_old(p) * 1024 + k]);
}

__global__ void k_prep_w2(const float* __restrict__ Wih2, const float* __restrict__ Whh2,
                          __hip_bfloat16* __restrict__ dst) {
    int i = blockIdx.x * blockDim.x + threadIdx.x;   // over 4096*2048
    int p = i >> 11, k = i & 2047;
    int old = perm_old(p);
    float v = (k < 1024) ? Wih2[(size_t)old * 1024 + k] : Whh2[(size_t)old * 1024 + (k - 1024)];
    dst[i] = __float2bfloat16(v);
}

__global__ void k_prep_vec(const float* __restrict__ bih1, const float* __restrict__ bhh1,
                           const float* __restrict__ bih2, const float* __restrict__ bhh2,
                           const float* __restrict__ Wih1,
                           float* __restrict__ b1p, float* __restrict__ b2p,
                           float* __restrict__ w1p) {
    int p = blockIdx.x * blockDim.x + threadIdx.x;
    if (p >= G4) return;
    int old = perm_old(p);
    b1p[p] = bih1[old] + bhh1[old];
    b2p[p] = bih2[old] + bhh2[old];
    w1p[p] = Wih1[old];
}

__global__ void k_xT(const float* __restrict__ x, float* __restrict__ xT) {
    int i = blockIdx.x * blockDim.x + threadIdx.x;   // over B*T
    if (i >= B_SZ * T_SZ) return;
    int b = i / T_SZ, t = i % T_SZ;
    xT[t * B_SZ + b] = x[i];
}

__global__ void k_init_state(const float* __restrict__ h1_0, const float* __restrict__ c1_0,
                             const float* __restrict__ h2_0, const float* __restrict__ c2_0,
                             __hip_bfloat16* __restrict__ A2_0, __hip_bfloat16* __restrict__ A2_1,
                             float* __restrict__ c1, float* __restrict__ c2) {
    int i = blockIdx.x * blockDim.x + threadIdx.x;   // over B*H
    if (i >= B_SZ * H_SZ) return;
    int b = i >> 10, j = i & 1023;
    A2_1[(size_t)b * 2048 + j]        = __float2bfloat16(h1_0[i]);
    A2_0[(size_t)b * 2048 + 1024 + j] = __float2bfloat16(h2_0[i]);
    c1[i] = c1_0[i];
    c2[i] = c2_0[i];
}

// ---------------- fused GEMM + LSTM cell, 256x256, asm-read m201 cadence ---------
// 8 waves (2M x 4N), per-wave 128x64 C, BK=64, LDS 2-buf 128 KiB.
// Quadrant phases (reads 12/4/8/0), ds_reads via opaque inline asm so the
// compiler cannot insert conservative vmcnt drains between global_load_lds and
// the LDS reads. Manual lgkmcnt(0)+sched_barrier(0) before each dependent MFMA
// cluster (rule #18). True m201 stage cadence, 1 half-tile unit per phase:
//   p1: U2[kt+1]->buf^1   (A-a1 rows; freed at kt-1 p3 on that buffer)
//   p2: U1[kt+2]->buf     (A-a0 rows; freed at kt p1)
//   p3: U3[kt+2]->buf     (B-b0 rows; freed at kt p1)
//   p4: U4[kt+2]->buf     (B-b1 rows; freed at kt p2)
// ONE binding wait per K-tile at p4-end: vmcnt(6) (FIFO: 7 units outstanding ->
// waits for 4; lands ALL of tile kt+1, keeps U1,U3,U4[kt+2] in flight).
// Tail: kt==NK-2 -> vmcnt(0); kt==NK-1 -> none.
#define BM 256
#define BN 256
#define BK 64

template<int LAYER>
__global__ __launch_bounds__(512, 2)
void k_gemm_cell(const __hip_bfloat16* __restrict__ A, int lda,
                 const __hip_bfloat16* __restrict__ Bw, int ldb, int K,
                 const float* __restrict__ biasp, const float* __restrict__ wih1p,
                 const float* __restrict__ xT, int t,
                 float* __restrict__ c, __hip_bfloat16* __restrict__ hout) {
    __shared__ short As[2][BM][BK];   // 64 KiB
    __shared__ short Bs[2][BN][BK];   // 64 KiB
    const int tid  = threadIdx.x;
    const int lane = tid & 63;
    const int wid  = tid >> 6;        // 0..7

    // XCD slab mapping (512 blocks): xcd = bid&7 owns a 16m x 4n slab,
    // within-slab m-fastest-over-8 -> ~8m x 4n concurrent group per XCD.
    const int bid = blockIdx.x;
    const int xcd = bid & 7;
    const int i   = bid >> 3;                      // 0..63
    const int ml  = (i & 7) | ((i >> 5) << 3);     // 0..15
    const int nl  = (i >> 3) & 3;                  // 0..3
    const int m0  = ((xcd & 1) * 16 + ml) * BM;
    const int n0  = ((xcd >> 1) * 4 + nl) * BN;

    const int wm = wid >> 2;          // 0..1
    const int wn = wid & 3;           // 0..3
    const int fr = lane & 15;
    const int kg = lane >> 4;

    const __hip_bfloat16* Abase = A  + (size_t)m0 * lda;
    const __hip_bfloat16* Bbase = Bw + (size_t)n0 * ldb;

    f32x4 acc[8][4];
#pragma unroll
    for (int ii = 0; ii < 8; ++ii)
#pragma unroll
        for (int j = 0; j < 4; ++j) acc[ii][j] = (f32x4)0.f;

    // staging: one global_load_lds covers 8 LDS rows; source col pre-swizzled
    // (chunk ^= row&7) so linear LDS dest + same-XOR read = involution (rule #21).
    auto stage8A = [&](int buf, int lr0, int kcol) {
        int lr = lr0 + (lane >> 3);
        int scol = (((lane & 7) ^ (lr & 7)) << 3);
        const __hip_bfloat16* gp = Abase + (size_t)lr * lda + kcol + scol;
        __builtin_amdgcn_global_load_lds(
            (const __attribute__((address_space(1))) void*)gp,
            (__attribute__((address_space(3))) void*)(&As[buf][lr0][0]), 16, 0, 0);
    };
    auto stage8B = [&](int buf, int lr0, int kcol) {
        int lr = lr0 + (lane >> 3);
        int scol = (((lane & 7) ^ (lr & 7)) << 3);
        const __hip_bfloat16* gp = Bbase + (size_t)lr * ldb + kcol + scol;
        __builtin_amdgcn_global_load_lds(
            (const __attribute__((address_space(1))) void*)gp,
            (__attribute__((address_space(3))) void*)(&Bs[buf][lr0][0]), 16, 0, 0);
    };
    auto stage_u1 = [&](int kt, int buf) {   // A rows (r%128)<64  (a0 rows)
#pragma unroll
        for (int j = 0; j < 2; ++j) {
            int rr0 = (wid * 2 + j) * 8;
            int lr0 = (rr0 < 64) ? rr0 : rr0 + 64;
            stage8A(buf, lr0, kt * BK);
        }
    };
    auto stage_u2 = [&](int kt, int buf) {   // A rows (r%128)>=64 (a1 rows)
#pragma unroll
        for (int j = 0; j < 2; ++j) {
            int rr0 = (wid * 2 + j) * 8;
            int lr0 = (rr0 < 64) ? rr0 + 64 : rr0 + 128;
            stage8A(buf, lr0, kt * BK);
        }
    };
    auto stage_u3 = [&](int kt, int buf) {   // B rows (r%64)<32   (b0 rows)
#pragma unroll
        for (int j = 0; j < 2; ++j) {
            int rr0 = (wid * 2 + j) * 8;
            int lr0 = ((rr0 >> 5) << 6) + (rr0 & 31);
            stage8B(buf, lr0, kt * BK);
        }
    };
    auto stage_u4 = [&](int kt, int buf) {   // B rows (r%64)>=32  (b1 rows)
#pragma unroll
        for (int j = 0; j < 2; ++j) {
            int rr0 = (wid * 2 + j) * 8;
            int lr0 = ((rr0 >> 5) << 6) + 32 + (rr0 & 31);
            stage8B(buf, lr0, kt * BK);
        }
    };

    // LDS byte-offset bases for asm ds_reads (AS3 pointer -> 32-bit offset)
    const unsigned asb = (unsigned)(uintptr_t)(__attribute__((address_space(3))) short*)&As[0][0][0];
    const unsigned bsb = (unsigned)(uintptr_t)(__attribute__((address_space(3))) short*)&Bs[0][0][0];
    const unsigned aoffB = (unsigned)((wm * 128 + fr) * 64) * 2;
    const unsigned boffB = (unsigned)((wn * 64 + fr) * 64) * 2;
    const unsigned ck0B  = (unsigned)((kg ^ (fr & 7)) << 3) * 2;
    const unsigned ck1B  = (unsigned)(((4 + kg) ^ (fr & 7)) << 3) * 2;

    const int NK = K >> 6;

    // ---- prologue: U1,U3,U4,U2[0] then U1,U3,U4[1] (14 loads) ----
    stage_u1(0, 0); stage_u3(0, 0); stage_u4(0, 0); stage_u2(0, 0);
    stage_u1(1, 1); stage_u3(1, 1); stage_u4(1, 1);
    asm volatile("s_waitcnt vmcnt(6)" ::: "memory");   // tile-0 fully landed
    __builtin_amdgcn_s_barrier();

    bf16x8 a0[4][2], a1[4][2], b0[2][2], b1[2][2];

    for (int kt = 0; kt < NK; ++kt) {
        const int buf = kt & 1;
        const unsigned bo = (unsigned)buf * 32768u;
        const unsigned bA0 = asb + bo + aoffB + ck0B;
        const unsigned bA1 = asb + bo + aoffB + ck1B;
        const unsigned bB0 = bsb + bo + boffB + ck0B;
        const unsigned bB1 = bsb + bo + boffB + ck1B;

        // ---------- phase 1: quadrant (mq0, nq0), 12 asm reads, stage U2[kt+1] ----------
        DSR(a0[0][0], bA0, 0);    DSR(a0[0][1], bA1, 0);
        DSR(a0[1][0], bA0, 2048); DSR(a0[1][1], bA1, 2048);
        DSR(a0[2][0], bA0, 4096); DSR(a0[2][1], bA1, 4096);
        DSR(a0[3][0], bA0, 6144); DSR(a0[3][1], bA1, 6144);
        DSR(b0[0][0], bB0, 0);    DSR(b0[0][1], bB1, 0);
        DSR(b0[1][0], bB0, 2048); DSR(b0[1][1], bB1, 2048);
        if (kt + 1 < NK) stage_u2(kt + 1, buf ^ 1);
        asm volatile("s_waitcnt lgkmcnt(8)" ::: "memory");
        __builtin_amdgcn_s_barrier();
        asm volatile("s_waitcnt lgkmcnt(0)" ::: "memory");
        __builtin_amdgcn_sched_barrier(0);
        __builtin_amdgcn_s_setprio(1);
#pragma unroll
        for (int ks = 0; ks < 2; ++ks)
#pragma unroll
            for (int m = 0; m < 4; ++m)
#pragma unroll
                for (int n = 0; n < 2; ++n)
                    acc[m][n] = __builtin_amdgcn_mfma_f32_16x16x32_bf16(a0[m][ks], b0[n][ks], acc[m][n], 0, 0, 0);
        __builtin_amdgcn_s_setprio(0);
        __builtin_amdgcn_s_barrier();

        // ---------- phase 2: quadrant (mq0, nq1), 4 asm reads, stage U1[kt+2] ----------
        DSR(b1[0][0], bB0, 4096); DSR(b1[0][1], bB1, 4096);
        DSR(b1[1][0], bB0, 6144); DSR(b1[1][1], bB1, 6144);
        if (kt + 2 < NK) stage_u1(kt + 2, buf);
        __builtin_amdgcn_s_barrier();
        asm volatile("s_waitcnt lgkmcnt(0)" ::: "memory");
        __builtin_amdgcn_sched_barrier(0);
        __builtin_amdgcn_s_setprio(1);
#pragma unroll
        for (int ks = 0; ks < 2; ++ks)
#pragma unroll
            for (int m = 0; m < 4; ++m)
#pragma unroll
                for (int n = 0; n < 2; ++n)
                    acc[m][2 + n] = __builtin_amdgcn_mfma_f32_16x16x32_bf16(a0[m][ks], b1[n][ks], acc[m][2 + n], 0, 0, 0);
        __builtin_amdgcn_s_setprio(0);
        __builtin_amdgcn_s_barrier();

        // ---------- phase 3: quadrant (mq1, nq0), 8 asm reads, stage U3[kt+2] ----------
        DSR(a1[0][0], bA0, 8192);  DSR(a1[0][1], bA1, 8192);
        DSR(a1[1][0], bA0, 10240); DSR(a1[1][1], bA1, 10240);
        DSR(a1[2][0], bA0, 12288); DSR(a1[2][1], bA1, 12288);
        DSR(a1[3][0], bA0, 14336); DSR(a1[3][1], bA1, 14336);
        if (kt + 2 < NK) stage_u3(kt + 2, buf);
        __builtin_amdgcn_s_barrier();
        asm volatile("s_waitcnt lgkmcnt(0)" ::: "memory");
        __builtin_amdgcn_sched_barrier(0);
        __builtin_amdgcn_s_setprio(1);
#pragma unroll
        for (int ks = 0; ks < 2; ++ks)
#pragma unroll
            for (int m = 0; m < 4; ++m)
#pragma unroll
                for (int n = 0; n < 2; ++n)
                    acc[4 + m][n] = __builtin_amdgcn_mfma_f32_16x16x32_bf16(a1[m][ks], b0[n][ks], acc[4 + m][n], 0, 0, 0);
        __builtin_amdgcn_s_setprio(0);
        __builtin_amdgcn_s_barrier();

        // ---------- phase 4: quadrant (mq1, nq1), 0 reads, stage U4[kt+2] ----------
        if (kt + 2 < NK) stage_u4(kt + 2, buf);
        __builtin_amdgcn_s_barrier();
        __builtin_amdgcn_s_setprio(1);
#pragma unroll
        for (int ks = 0; ks < 2; ++ks)
#pragma unroll
            for (int m = 0; m < 4; ++m)
#pragma unroll
                for (int n = 0; n < 2; ++n)
                    acc[4 + m][2 + n] = __builtin_amdgcn_mfma_f32_16x16x32_bf16(a1[m][ks], b1[n][ks], acc[4 + m][2 + n], 0, 0, 0);
        __builtin_amdgcn_s_setprio(0);
        if (kt + 2 < NK)      asm volatile("s_waitcnt vmcnt(6)" ::: "memory");  // binding: lands tile kt+1
        else if (kt + 1 < NK) asm volatile("s_waitcnt vmcnt(0)" ::: "memory");  // tail drain
        __builtin_amdgcn_s_barrier();
    }

    // ---- fused cell epilogue ----
    float biasv[4], xwv[4];
#pragma unroll
    for (int n = 0; n < 4; ++n) {
        int col = n0 + wn * 64 + n * 16 + fr;
        biasv[n] = biasp[col];
        if (LAYER == 1) xwv[n] = wih1p[col];
    }
    const int u = ((n0 >> 6) + wn) * 16 + fr;   // global unit index 0..1023

#pragma unroll
    for (int m = 0; m < 8; ++m) {
        int rbase = m0 + wm * 128 + m * 16 + (lane >> 4) * 4;
#pragma unroll
        for (int j = 0; j < 4; ++j) {
            int b = rbase + j;
            float gi = acc[m][0][j] + biasv[0];
            float gf = acc[m][1][j] + biasv[1];
            float gg = acc[m][2][j] + biasv[2];
            float go = acc[m][3][j] + biasv[3];
            if (LAYER == 1) {
                float xv = xT[t * B_SZ + b];
                gi += xv * xwv[0];
                gf += xv * xwv[1];
                gg += xv * xwv[2];
                go += xv * xwv[3];
            }
            float si = fast_sigmoid(gi);
            float sf = fast_sigmoid(gf);
            float so = fast_sigmoid(go);
            float tg = fast_tanh(gg);
            size_t ci = (size_t)b * H_SZ + u;
            float cn = sf * c[ci] + si * tg;
            c[ci] = cn;
            hout[(size_t)b * 2048 + u] = __float2bfloat16(so * fast_tanh(cn));
        }
    }
}

// ---------------- output projection ----------------
__global__ __launch_bounds__(256)
void k_out(const __hip_bfloat16* __restrict__ h2base, const float* __restrict__ Wout,
           const float* __restrict__ bout, float* __restrict__ out) {
    int gw   = (blockIdx.x * blockDim.x + threadIdx.x) >> 6;
    int lane = threadIdx.x & 63;
    if (gw >= B_SZ) return;
    const __hip_bfloat16* h = h2base + (size_t)gw * 2048;
    float a0 = 0.f, a1 = 0.f;
#pragma unroll
    for (int k = lane; k < 1024; k += 64) {
        float hv = __bfloat162float(h[k]);
        a0 += hv * Wout[k];
        a1 += hv * Wout[1024 + k];
    }
    for (int off = 32; off; off >>= 1) {
        a0 += __shfl_down(a0, off);
        a1 += __shfl_down(a1, off);
    }
    if (lane == 0) {
        out[gw * 2 + 0] = a0 + bout[0];
        out[gw * 2 + 1] = a1 + bout[1];
    }
}

extern "C" void kernel_launch(void* const* d_in, const int* in_sizes, int n_in,
                              void* d_out, int out_size, void* d_ws, size_t ws_size,
                              hipStream_t stream) {
    const float* x    = (const float*)d_in[0];
    const float* h1_0 = (const float*)d_in[1];
    const float* c1_0 = (const float*)d_in[2];
    const float* h2_0 = (const float*)d_in[3];
    const float* c2_0 = (const float*)d_in[4];
    const float* Wih1 = (const float*)d_in[5];
    const float* Whh1 = (const float*)d_in[6];
    const float* bih1 = (const float*)d_in[7];
    const float* bhh1 = (const float*)d_in[8];
    const float* Wih2 = (const float*)d_in[9];
    const float* Whh2 = (const float*)d_in[10];
    const float* bih2 = (const float*)d_in[11];
    const float* bhh2 = (const float*)d_in[12];
    const float* Wout = (const float*)d_in[13];
    const float* bout = (const float*)d_in[14];
    float* out = (float*)d_out;
    (void)in_sizes; (void)n_in; (void)out_size; (void)ws_size;

    uint8_t* ws = (uint8_t*)d_ws;
    size_t off = 0;
    auto alloc = [&](size_t bytes) { void* p = ws + off; off += (bytes + 255) & ~(size_t)255; return p; };
    __hip_bfloat16* A2_0  = (__hip_bfloat16*)alloc((size_t)B_SZ * 2048 * 2);
    __hip_bfloat16* A2_1  = (__hip_bfloat16*)alloc((size_t)B_SZ * 2048 * 2);
    float*          c1    = (float*)alloc((size_t)B_SZ * H_SZ * 4);
    float*          c2    = (float*)alloc((size_t)B_SZ * H_SZ * 4);
    __hip_bfloat16* Whh1p = (__hip_bfloat16*)alloc((size_t)G4 * H_SZ * 2);
    __hip_bfloat16* Wcat2p= (__hip_bfloat16*)alloc((size_t)G4 * 2048 * 2);
    float*          bias1p= (float*)alloc(G4 * 4);
    float*          bias2p= (float*)alloc(G4 * 4);
    float*          wih1p = (float*)alloc(G4 * 4);
    float*          xT    = (float*)alloc((size_t)T_SZ * B_SZ * 4);

    __hip_bfloat16* A2[2] = { A2_0, A2_1 };

    k_prep_w1<<<(G4 * H_SZ + 255) / 256, 256, 0, stream>>>(Whh1, Whh1p);
    k_prep_w2<<<(G4 * 2048 + 255) / 256, 256, 0, stream>>>(Wih2, Whh2, Wcat2p);
    k_prep_vec<<<(G4 + 255) / 256, 256, 0, stream>>>(bih1, bhh1, bih2, bhh2, Wih1,
                                                     bias1p, bias2p, wih1p);
    k_xT<<<(B_SZ * T_SZ + 255) / 256, 256, 0, stream>>>(x, xT);
    k_init_state<<<(B_SZ * H_SZ + 255) / 256, 256, 0, stream>>>(h1_0, c1_0, h2_0, c2_0,
                                                                A2_0, A2_1, c1, c2);

    const int gemm_blocks = (B_SZ / BM) * (G4 / BN);   // 512

    for (int t = 0; t < T_SZ; ++t) {
        __hip_bfloat16* Pprev = A2[(t + 1) & 1];   // P_{t-1}
        __hip_bfloat16* Pt    = A2[t & 1];         // P_t
        // layer 1: reads h1_{t-1} (Pprev first half), writes h1_t -> Pt first half
        k_gemm_cell<1><<<gemm_blocks, 512, 0, stream>>>(
            (const __hip_bfloat16*)Pprev, 2048, Whh1p, 1024, 1024,
            bias1p, wih1p, xT, t, c1, Pt);
        // layer 2: reads [h1_t | h2_{t-1}] = Pt, writes h2_t -> P_{t+1} second half
        k_gemm_cell<2><<<gemm_blocks, 512, 0, stream>>>(
            (const __hip_bfloat16*)Pt, 2048, Wcat2p, 2048, 2048,
            bias2p, nullptr, nullptr, 0, c2, A2[(t + 1) & 1] + 1024);
    }
    // final h2 is in P_24 = A2[0] second half (T=24 even)
    k_out<<<(B_SZ * 64 + 255) / 256, 256, 0, stream>>>(A2_0 + 1024, Wout, bout, out);
}